// Round 13
// baseline (665.777 us; speedup 1.0000x reference)
//
#include <hip/hip_runtime.h>
#include <hip/hip_fp16.h>
#include <cstddef>
#include <cstdint>

constexpr int DIMS = 128;
constexpr float BN_EPS = 1e-5f;
constexpr int NSH = 64;    // stat shadow copies
constexpr int GB2 = 2048;  // gather grid blocks (x4 waves = 8192 waves)
constexpr int NPB = 512;   // partition blocks for CSR build

typedef _Float16 f16x8 __attribute__((ext_vector_type(8)));
typedef float f32x4 __attribute__((ext_vector_type(4)));

static __device__ __forceinline__ f16x8 as_f16x8(uint4 u) {
  union { uint4 u; f16x8 h; } x; x.u = u; return x.h;
}
static __device__ __forceinline__ __half2 as_h2(uint32_t u) {
  union { uint32_t u; __half2 h; } x; x.u = u; return x.h;
}
static __device__ __forceinline__ uint32_t h2bits(__half2 h) {
  union { __half2 h; uint32_t u; } x; x.h = h; return x.u;
}

// ---------------- utility ----------------
__global__ void zero_k(float* __restrict__ fp, size_t nf) {
  size_t i = (size_t)blockIdx.x * blockDim.x + threadIdx.x;
  if (i < nf) fp[i] = 0.f;
}

// fp32 -> fp16 with dn pre-scale, SLICE-MAJOR output:
// out[(slice*n + node)*8 + w] where slice = wglob>>3, w = wglob&7
__global__ void cvt_k(const float2* __restrict__ in2, uint32_t* __restrict__ out,
                      const float* __restrict__ dnorm, int n) {
  size_t total = (size_t)n * 64;
  size_t i = (size_t)blockIdx.x * blockDim.x + threadIdx.x;
  size_t stride = (size_t)gridDim.x * blockDim.x;
  for (; i < total; i += stride) {
    int nd = (int)(i >> 6);
    int wg = (int)(i & 63);
    float d = dnorm[nd];
    float2 v = in2[i];
    out[((size_t)(wg >> 3) * n + nd) * 8 + (wg & 7)] =
        h2bits(__floats2half2_rn(v.x * d, v.y * d));
  }
}

// ---------------- two-pass binned CSR build (no global atomics) ----------------
// bins of 512 nodes; nbins <= 512 (n <= 262144). C layout: C[block*512 + bin].

__global__ __launch_bounds__(256) void cnt_k(const int* __restrict__ dst,
                                             int* __restrict__ C, int e, int chunk) {
  __shared__ int hist[512];
  int b = blockIdx.x;
  for (int j = threadIdx.x; j < 512; j += 256) hist[j] = 0;
  __syncthreads();
  int i0 = b * chunk;
  int i1 = i0 + chunk; if (i1 > e) i1 = e;
  for (int i = i0 + threadIdx.x; i < i1; i += 256)
    atomicAdd(&hist[dst[i] >> 9], 1);
  __syncthreads();
  for (int j = threadIdx.x; j < 512; j += 256) C[b * 512 + j] = hist[j];
}

__global__ __launch_bounds__(512) void colscan_k(int* __restrict__ C, int* __restrict__ tot) {
  int j = blockIdx.x;   // bin
  int t = threadIdx.x;  // partition block
  int v = C[t * 512 + j];
  __shared__ int lds[512];
  lds[t] = v; __syncthreads();
  for (int off = 1; off < 512; off <<= 1) {
    int add = (t >= off) ? lds[t - off] : 0;
    __syncthreads();
    lds[t] += add;
    __syncthreads();
  }
  C[t * 512 + j] = lds[t] - v;  // exclusive within-column prefix
  if (t == 511) tot[j] = lds[511];
}

__global__ __launch_bounds__(512) void bscan_k(const int* __restrict__ tot, int nbins,
                                               int* __restrict__ boff, int* __restrict__ adj,
                                               int e) {
  int t = threadIdx.x;
  int v = tot[t];
  __shared__ int lds[512];
  lds[t] = v; __syncthreads();
  for (int off = 1; off < 512; off <<= 1) {
    int add = (t >= off) ? lds[t - off] : 0;
    __syncthreads();
    lds[t] += add;
    __syncthreads();
  }
  boff[t] = lds[t] - v;
  if (t == 0) boff[nbins] = e;
  if (t < 16) adj[e + t] = 0;  // harmless pad
}

// scatter edges to bin-grouped ebin using LDS-only cursors
__global__ __launch_bounds__(512) void scat_k(const int* __restrict__ src,
                                              const int* __restrict__ dst,
                                              const int* __restrict__ C,
                                              const int* __restrict__ boff,
                                              int* __restrict__ ebin, int e, int chunk) {
  __shared__ int cur[512];
  int b = blockIdx.x;
  int t = threadIdx.x;
  cur[t] = boff[t] + C[b * 512 + t];
  __syncthreads();
  int i0 = b * chunk;
  int i1 = i0 + chunk; if (i1 > e) i1 = e;
  for (int i = i0 + t; i < i1; i += 512) {
    int d = dst[i];
    int bin = d >> 9;
    int p = atomicAdd(&cur[bin], 1);
    ebin[p] = (src[i] << 9) | (d & 511);
  }
}

// fused per-bin: degree histogram -> LDS scan -> row_off + dnorm
__global__ __launch_bounds__(512) void binidx_k(
    const int* __restrict__ ebin, const int* __restrict__ boff,
    int* __restrict__ row_off, float* __restrict__ dnorm, int n, int nbins) {
  __shared__ int cnt[512];
  __shared__ int scn[512];
  int b = blockIdx.x;
  int t = threadIdx.x;
  cnt[t] = 0;
  __syncthreads();
  int j0 = boff[b], j1 = boff[b + 1];
  for (int i = j0 + t; i < j1; i += 512) atomicAdd(&cnt[ebin[i] & 511], 1);
  __syncthreads();
  int v = cnt[t];
  scn[t] = v; __syncthreads();
  for (int off = 1; off < 512; off <<= 1) {
    int add = (t >= off) ? scn[t - off] : 0;
    __syncthreads();
    scn[t] += add;
    __syncthreads();
  }
  int node = (b << 9) + t;
  if (node < n) {
    row_off[node] = j0 + scn[t] - v;
    dnorm[node] = rsqrtf(fmaxf((float)v, 1.0f));
  }
  if (b == nbins - 1 && t == 0) row_off[n] = j1;  // j1 == e for last bin
}

// adj placement (bin-local, L2-hot) + wsum[node] = sum dn[src] via LDS accumulators
__global__ __launch_bounds__(512) void adj_bins_k(
    const int* __restrict__ ebin, const int* __restrict__ boff,
    const int* __restrict__ row_off, const float* __restrict__ dnorm,
    int* __restrict__ adj, float* __restrict__ wsum, int n) {
  __shared__ int cur[512];
  __shared__ int ro[512];
  __shared__ float ws[512];
  int b = blockIdx.x;
  int base = b << 9;
  int t = threadIdx.x;
  {
    cur[t] = 0;
    ws[t] = 0.f;
    int node = base + t;
    ro[t] = (node < n) ? row_off[node] : 0;
  }
  __syncthreads();
  int j0 = boff[b], j1 = boff[b + 1];
  for (int i = j0 + t; i < j1; i += 512) {
    int pk = ebin[i];
    int dl = pk & 511;
    int s = pk >> 9;
    int p = atomicAdd(&cur[dl], 1);
    adj[ro[dl] + p] = s;
    atomicAdd(&ws[dl], dnorm[s]);
  }
  __syncthreads();
  {
    int node = base + t;
    if (node < n) wsum[node] = ws[t];
  }
}

// ---------------- propagation hop: 8 sequential SLICE sweeps per hop ----------------
// Sweep handles 16 features (8 words) of every node; per-sweep gather footprint is
// n*32B = 4.8 MB, sized to fit the 4 MiB per-XCD L2 (every L2 caches the slice).
// Wave = 8 edge-slots x 8 word-lanes; 2 sub-batches x 2 node streams in flight.
// AFF=false (hop1): acc = sum Xp[s]; v = dn*acc (stats); store W1 = dn^2*acc.
// AFF=true  (hop2): acc = sum W1[s]; v = dn*(a*acc + b*wsum[n]) (stats); store v.
template <bool AFF>
__global__ __launch_bounds__(256) void gather_k(
    const uint32_t* __restrict__ Xu, uint32_t* __restrict__ Yout,
    const int* __restrict__ row_off, const int* __restrict__ adj,
    const float* __restrict__ dn, const float* __restrict__ wsum,
    const float* __restrict__ a, const float* __restrict__ b,
    float* __restrict__ sumS, float* __restrict__ sqS, int n, int nwaves, int slice) {
  int tid = threadIdx.x;
  int l = tid & 63, w = tid >> 6;
  int wid = blockIdx.x * 4 + w;  // wave-uniform
  int es = l >> 3;               // edge slot 0..7
  uint32_t wl = (uint32_t)(l & 7);  // word slot (2 features)
  const size_t SBASE = (size_t)slice * n;  // in 8-word rows
  int f0 = slice * 16 + 2 * (int)wl;
  float af0 = 1.f, bf0 = 0.f, af1 = 1.f, bf1 = 0.f;
  if (AFF) { af0 = a[f0]; bf0 = b[f0]; af1 = a[f0 + 1]; bf1 = b[f0 + 1]; }
  float s0 = 0.f, s1 = 0.f, q0 = 0.f, q1 = 0.f;

  for (int nodeA = wid; nodeA < n; nodeA += 2 * nwaves) {
    const int nodeB = nodeA + nwaves;
    const bool hasB = nodeB < n;
    int ja = row_off[nodeA];
    const int ea = row_off[nodeA + 1];
    int jb = hasB ? row_off[nodeB] : 0;
    const int eb = hasB ? row_off[nodeB + 1] : 0;
    float accA0 = 0.f, accA1 = 0.f, accB0 = 0.f, accB1 = 0.f;

    while ((ja < ea) || (jb < eb)) {
      uint32_t xa[2], xb[2];
      const bool runA = ja < ea, runB = jb < eb;
      if (runA) {  // 2 sub-batches x 8 edges for stream A
#pragma unroll
        for (int t2 = 0; t2 < 2; ++t2) {
          int jj = ja + 8 * t2 + es;
          int jc = jj < ea ? jj : ea - 1;  // clamp: no junk fetches
          uint32_t sj = (uint32_t)adj[jc];
          uint32_t v = Xu[(SBASE + sj) * 8 + wl];
          xa[t2] = (jj < ea) ? v : 0u;
        }
      }
      if (runB) {
#pragma unroll
        for (int t2 = 0; t2 < 2; ++t2) {
          int jj = jb + 8 * t2 + es;
          int jc = jj < eb ? jj : eb - 1;
          uint32_t sj = (uint32_t)adj[jc];
          uint32_t v = Xu[(SBASE + sj) * 8 + wl];
          xb[t2] = (jj < eb) ? v : 0u;
        }
      }
      if (runA) {
        float2 u = __half22float2(__hadd2(as_h2(xa[0]), as_h2(xa[1])));
        accA0 += u.x; accA1 += u.y;
        ja += 16;
      }
      if (runB) {
        float2 u = __half22float2(__hadd2(as_h2(xb[0]), as_h2(xb[1])));
        accB0 += u.x; accB1 += u.y;
        jb += 16;
      }
    }

    // reduce across the 8 edge slots (es axis = lane bits 3..5)
    accA0 += __shfl_xor(accA0, 8);  accA0 += __shfl_xor(accA0, 16); accA0 += __shfl_xor(accA0, 32);
    accA1 += __shfl_xor(accA1, 8);  accA1 += __shfl_xor(accA1, 16); accA1 += __shfl_xor(accA1, 32);
    if (hasB) {
      accB0 += __shfl_xor(accB0, 8);  accB0 += __shfl_xor(accB0, 16); accB0 += __shfl_xor(accB0, 32);
      accB1 += __shfl_xor(accB1, 8);  accB1 += __shfl_xor(accB1, 16); accB1 += __shfl_xor(accB1, 32);
    }

    {  // finalize node A
      float dnn = dn[nodeA];
      float v0, v1;
      if constexpr (AFF) {
        float wsn = wsum[nodeA];
        v0 = dnn * fmaf(af0, accA0, bf0 * wsn);
        v1 = dnn * fmaf(af1, accA1, bf1 * wsn);
        if (es == 0)
          Yout[(SBASE + nodeA) * 8 + wl] = h2bits(__floats2half2_rn(v0, v1));
      } else {
        v0 = dnn * accA0;
        v1 = dnn * accA1;
        if (es == 0)  // W1 = dn^2*acc
          Yout[(SBASE + nodeA) * 8 + wl] = h2bits(__floats2half2_rn(v0 * dnn, v1 * dnn));
      }
      s0 += v0; s1 += v1; q0 += v0 * v0; q1 += v1 * v1;
    }
    if (hasB) {  // finalize node B
      float dnn = dn[nodeB];
      float v0, v1;
      if constexpr (AFF) {
        float wsn = wsum[nodeB];
        v0 = dnn * fmaf(af0, accB0, bf0 * wsn);
        v1 = dnn * fmaf(af1, accB1, bf1 * wsn);
        if (es == 0)
          Yout[(SBASE + nodeB) * 8 + wl] = h2bits(__floats2half2_rn(v0, v1));
      } else {
        v0 = dnn * accB0;
        v1 = dnn * accB1;
        if (es == 0)
          Yout[(SBASE + nodeB) * 8 + wl] = h2bits(__floats2half2_rn(v0 * dnn, v1 * dnn));
      }
      s0 += v0; s1 += v1; q0 += v0 * v0; q1 += v1 * v1;
    }
  }

  // epilogue: es==0 lanes carry this slice's 16-feature stats; 32 atomics/block
  __shared__ float red[4][32];
  if (es == 0) {
    red[w][0 * 8 + wl] = s0;
    red[w][1 * 8 + wl] = s1;
    red[w][2 * 8 + wl] = q0;
    red[w][3 * 8 + wl] = q1;
  }
  __syncthreads();
  if (tid < 32) {
    float v = red[0][tid] + red[1][tid] + red[2][tid] + red[3][tid];
    int comp = tid >> 3, ws2 = tid & 7;
    int f = slice * 16 + 2 * ws2 + (comp & 1);
    float* dstp = (comp & 2) ? sqS : sumS;
    atomicAdd(&dstp[(blockIdx.x & (NSH - 1)) * DIMS + f], v);
  }
}

// ---------------- BN affine coefficients (reduces NSH shadow copies) ----------------
__global__ void affine_k(const float* __restrict__ sum, const float* __restrict__ sq,
                         const float* __restrict__ gamma, const float* __restrict__ beta,
                         float* __restrict__ a, float* __restrict__ b, float invn) {
  int d = threadIdx.x;
  float s = 0.f, q = 0.f;
  for (int k = 0; k < NSH; ++k) { s += sum[k * DIMS + d]; q += sq[k * DIMS + d]; }
  float mu = s * invn;
  float var = q * invn - mu * mu;
  float rs = rsqrtf(var + BN_EPS);
  float ad = rs * gamma[d];
  a[d] = ad;
  b[d] = beta[d] - mu * ad;
}

// fold pre-matmul affine into weights, TRANSPOSED fp16:
// Wt[o][d] = (half)(a2[d]*W[d][o]);  cp[o] = sum_d b2[d]*W[d][o] + cb[o]
__global__ void foldw_k(const float* __restrict__ W, const float* __restrict__ cb,
                        const float* __restrict__ a2, const float* __restrict__ b2,
                        __half* __restrict__ Wt, float* __restrict__ cp) {
  int o = blockIdx.x;
  int d = threadIdx.x;
  float w = W[d * DIMS + o];
  Wt[o * DIMS + d] = __float2half(a2[d] * w);
  __shared__ float red[128];
  red[d] = b2[d] * w;
  __syncthreads();
  for (int off = 64; off > 0; off >>= 1) {
    if (d < off) red[d] += red[d + off];
    __syncthreads();
  }
  if (d == 0) cp[o] = red[0] + cb[o];
}

// ---------------- Z = X @ W + cp via MFMA, 32 rows/wave, LDS-staged stores ----------
// X (Y2) is SLICE-MAJOR: uint4 index u (0..15) of a row -> slice u>>1, sub u&1:
//   addr_in_uint4 = ((u>>1)*n + row)*2 + (u&1)
__global__ __launch_bounds__(256) void matmul_k(
    const uint4* __restrict__ X, const uint4* __restrict__ Wt,
    const float* __restrict__ cp, uint4* __restrict__ Z,
    float* __restrict__ sumS, float* __restrict__ sqS, int n) {
  int tid = threadIdx.x;
  int l = tid & 63, w = tid >> 6;
  int rowg = l & 15;  // A-row / B-col / D-col within tile
  int kg = l >> 4;    // k-group
  int r0 = (blockIdx.x * 4 + w) * 32;
  bool active = r0 < n;

  __shared__ __half outs[4][16][136];  // per-wave staging, +8 halves row pad
  __shared__ float sred[4][128], qred[4][128];
  float svals[8], qvals[8];

  if (active) {
    f32x4 acc0[8] = {}, acc1[8] = {};
    int row0 = r0 + rowg, row1 = r0 + 16 + rowg;
    bool ok0 = row0 < n;
    bool ok1 = row1 < n;
#pragma unroll
    for (int kk = 0; kk < 4; ++kk) {
#pragma unroll
      for (int dummy = 0; dummy < 1; ++dummy) {}  // keep structure flat
      int u = kk * 4 + kg;
      size_t base = ((size_t)(u >> 1) * n) * 2 + (u & 1);
      uint4 au0 = ok0 ? X[base + (size_t)row0 * 2] : make_uint4(0u, 0u, 0u, 0u);
      uint4 au1 = ok1 ? X[base + (size_t)row1 * 2] : make_uint4(0u, 0u, 0u, 0u);
      f16x8 a0 = as_f16x8(au0), a1 = as_f16x8(au1);
#pragma unroll
      for (int c = 0; c < 8; ++c) {
        f16x8 bfr = as_f16x8(Wt[(size_t)(c * 16 + rowg) * 16 + kk * 4 + kg]);
        acc0[c] = __builtin_amdgcn_mfma_f32_16x16x32_f16(a0, bfr, acc0[c], 0, 0, 0);
        acc1[c] = __builtin_amdgcn_mfma_f32_16x16x32_f16(a1, bfr, acc1[c], 0, 0, 0);
      }
    }
#pragma unroll
    for (int c = 0; c < 8; ++c) { svals[c] = 0.f; qvals[c] = 0.f; }
#pragma unroll
    for (int gidx = 0; gidx < 2; ++gidx) {
      int rbase = r0 + gidx * 16;
#pragma unroll
      for (int c = 0; c < 8; ++c) {
        float cpv = cp[c * 16 + rowg];
        f32x4 av = (gidx == 0) ? acc0[c] : acc1[c];
#pragma unroll
        for (int r = 0; r < 4; ++r) {
          int row = rbase + kg * 4 + r;
          float vv = av[r] + cpv;
          vv = (row < n) ? vv : 0.f;
          svals[c] += vv; qvals[c] += vv * vv;
          outs[w][kg * 4 + r][c * 16 + rowg] = __float2half(vv);
        }
      }
#pragma unroll
      for (int it = 0; it < 4; ++it) {
        int lr = it * 4 + kg;
        int grow = rbase + lr;
        if (grow < n)
          Z[(size_t)grow * 16 + rowg] = *(const uint4*)&outs[w][lr][rowg * 8];
      }
    }
#pragma unroll
    for (int c = 0; c < 8; ++c) {
      svals[c] += __shfl_xor(svals[c], 16); svals[c] += __shfl_xor(svals[c], 32);
      qvals[c] += __shfl_xor(qvals[c], 16); qvals[c] += __shfl_xor(qvals[c], 32);
    }
  }
  if (active) {
    if (kg == 0) {
#pragma unroll
      for (int c = 0; c < 8; ++c) {
        sred[w][c * 16 + rowg] = svals[c];
        qred[w][c * 16 + rowg] = qvals[c];
      }
    }
  } else {
    sred[w][l] = 0.f; sred[w][64 + l] = 0.f;
    qred[w][l] = 0.f; qred[w][64 + l] = 0.f;
  }
  __syncthreads();
  int f = tid & 127;
  int sh = blockIdx.x & (NSH - 1);
  if (tid < 128) {
    float s = sred[0][f] + sred[1][f] + sred[2][f] + sred[3][f];
    atomicAdd(&sumS[sh * DIMS + f], s);
  } else {
    float q = qred[0][f] + qred[1][f] + qred[2][f] + qred[3][f];
    atomicAdd(&sqS[sh * DIMS + f], q);
  }
}

// ---------------- graph segment starts (node2graph is sorted) ----------------
__global__ void gstart_k(const int* __restrict__ n2g, int* __restrict__ gstart, int n, int G) {
  int i = blockIdx.x * blockDim.x + threadIdx.x;
  if (i >= n) return;
  int g = n2g[i];
  int gp = (i == 0) ? -1 : n2g[i - 1];
  for (int x = gp + 1; x <= g; ++x) gstart[x] = i;
  if (i == n - 1) {
    for (int x = g + 1; x <= G; ++x) gstart[x] = n;
  }
}

// ---------------- BN2-apply + relu + mean-pool + 128->2 projection ----------------
__global__ __launch_bounds__(512) void pool_pred_k(
    const uint4* __restrict__ Z, const int* __restrict__ gstart,
    const float* __restrict__ a3, const float* __restrict__ b3,
    const float* __restrict__ pw, const float* __restrict__ pb,
    float* __restrict__ out) {
  int g = blockIdx.x;
  int tid = threadIdx.x;
  int l = tid & 63, w = tid >> 6;  // w 0..7
  int grp = l >> 4, fl = l & 15;
  int f0 = fl * 8;
  float av[8], bv[8];
#pragma unroll
  for (int q = 0; q < 8; ++q) { av[q] = a3[f0 + q]; bv[q] = b3[f0 + q]; }
  int s = gstart[g], e = gstart[g + 1];
  float rs[8] = {0.f, 0.f, 0.f, 0.f, 0.f, 0.f, 0.f, 0.f};
  for (int ni = s + (w * 4 + grp); ni < e; ni += 32) {
    uint4 zv = Z[(size_t)ni * 16 + fl];
    const __half2* h = (const __half2*)&zv;
#pragma unroll
    for (int q = 0; q < 4; ++q) {
      float2 z = __half22float2(h[q]);
      rs[2 * q] += fmaxf(fmaf(z.x, av[2 * q], bv[2 * q]), 0.f);
      rs[2 * q + 1] += fmaxf(fmaf(z.y, av[2 * q + 1], bv[2 * q + 1]), 0.f);
    }
  }
  float p0 = 0.f, p1 = 0.f;
#pragma unroll
  for (int q = 0; q < 8; ++q) {
    p0 += rs[q] * pw[(f0 + q) * 2 + 0];
    p1 += rs[q] * pw[(f0 + q) * 2 + 1];
  }
  __shared__ float r[2][512];
  r[0][tid] = p0; r[1][tid] = p1;
  __syncthreads();
  for (int off = 256; off > 0; off >>= 1) {
    if (tid < off) { r[0][tid] += r[0][tid + off]; r[1][tid] += r[1][tid + off]; }
    __syncthreads();
  }
  if (tid == 0) {
    float inv = 1.f / fmaxf((float)(e - s), 1.f);
    out[g * 2 + 0] = r[0][0] * inv + pb[0];
    out[g * 2 + 1] = r[1][0] * inv + pb[1];
  }
}

// ---------------- host launch ----------------
extern "C" void kernel_launch(void* const* d_in, const int* in_sizes, int n_in,
                              void* d_out, int out_size, void* d_ws, size_t ws_size,
                              hipStream_t stream) {
  const float* nfeat  = (const float*)d_in[0];
  const int*   src    = (const int*)d_in[1];
  const int*   dst    = (const int*)d_in[2];
  const int*   n2g    = (const int*)d_in[3];
  // d_in[4] = num_graphs (device scalar) — derived from out_size instead
  const float* conv_w = (const float*)d_in[5];
  const float* conv_b = (const float*)d_in[6];
  const float* gamma1 = (const float*)d_in[7];
  const float* beta1  = (const float*)d_in[8];
  const float* gamma2 = (const float*)d_in[9];
  const float* beta2  = (const float*)d_in[10];
  const float* pred_w = (const float*)d_in[11];
  const float* pred_b = (const float*)d_in[12];
  float* out = (float*)d_out;
  (void)n_in; (void)ws_size;

  const int n = in_sizes[0] / DIMS;
  const int e = in_sizes[1];
  const int g = out_size / 2;
  const int nbins = (n + 511) >> 9;  // <= 512 (n <= 262144)

  char* p = (char*)d_ws;
  auto alloc = [&](size_t bytes) { char* r = p; p += (bytes + 255) & ~(size_t)255; return r; };
  uint32_t* Xp  = (uint32_t*)alloc((size_t)n * 64 * 4);  // slice-major fp16 rows
  uint32_t* W1  = (uint32_t*)alloc((size_t)n * 64 * 4);  // slice-major dn^2*h1
  uint32_t* Y2  = (uint32_t*)alloc((size_t)n * 64 * 4);  // slice-major h2
  __half*   Zh  = (__half*)alloc((size_t)n * 64 * 4);    // row-major matmul output
  float* dnorm = (float*)alloc((size_t)n * 4);
  float* stat  = (float*)alloc(((size_t)6 * NSH * DIMS + n) * 4);  // stats + wsum
  float* wsum  = stat + 6 * NSH * DIMS;
  float* affA  = (float*)alloc(3 * DIMS * 4);
  float* affB  = (float*)alloc(3 * DIMS * 4);
  __half* Wt   = (__half*)alloc(DIMS * DIMS * 2);
  float* cp    = (float*)alloc(DIMS * 4);
  int* row_off = (int*)alloc(((size_t)n + 1) * 4);
  int* adj     = (int*)alloc(((size_t)e + 16) * 4);  // +16 pad
  int* ebin    = (int*)alloc((size_t)e * 4);
  int* Cmat    = (int*)alloc((size_t)NPB * 512 * 4);
  int* tot     = (int*)alloc(512 * 4);
  int* boff    = (int*)alloc(520 * 4);
  int* gstart  = (int*)alloc(((size_t)g + 1) * 4);

  const int SLAB = NSH * DIMS;
  float* S0 = stat + 0 * SLAB; float* Q0 = stat + 1 * SLAB;
  float* S1 = stat + 2 * SLAB; float* Q1 = stat + 3 * SLAB;
  float* S2 = stat + 4 * SLAB; float* Q2 = stat + 5 * SLAB;

  const float invn = 1.0f / (float)n;
  const int nwaves = GB2 * 4;
  const int chunk = (e + NPB - 1) / NPB;

  // zero stats
  zero_k<<<dim3(((size_t)6 * SLAB + 255) / 256), dim3(256), 0, stream>>>(stat, (size_t)6 * SLAB);
  // two-pass binned CSR build (no global atomics)
  cnt_k<<<dim3(NPB), dim3(256), 0, stream>>>(dst, Cmat, e, chunk);
  colscan_k<<<dim3(512), dim3(512), 0, stream>>>(Cmat, tot);
  bscan_k<<<dim3(1), dim3(512), 0, stream>>>(tot, nbins, boff, adj, e);
  scat_k<<<dim3(NPB), dim3(512), 0, stream>>>(src, dst, Cmat, boff, ebin, e, chunk);
  binidx_k<<<dim3(nbins), dim3(512), 0, stream>>>(ebin, boff, row_off, dnorm, n, nbins);
  cvt_k<<<dim3(2048), dim3(256), 0, stream>>>((const float2*)nfeat, Xp, dnorm, n);
  adj_bins_k<<<dim3(nbins), dim3(512), 0, stream>>>(ebin, boff, row_off, dnorm, adj, wsum, n);

  // hop 1: Xp -> W1, 8 slice sweeps (stats -> S0/Q0)
  for (int s = 0; s < 8; ++s)
    gather_k<false><<<dim3(GB2), dim3(256), 0, stream>>>(
        Xp, W1, row_off, adj, dnorm, wsum, nullptr, nullptr, S0, Q0, n, nwaves, s);
  affine_k<<<dim3(1), dim3(DIMS), 0, stream>>>(S0, Q0, gamma1, beta1, affA + 0, affB + 0, invn);
  // hop 2: W1 -> Y2, 8 slice sweeps (stats -> S1/Q1)
  for (int s = 0; s < 8; ++s)
    gather_k<true><<<dim3(GB2), dim3(256), 0, stream>>>(
        W1, Y2, row_off, adj, dnorm, wsum, affA + 0, affB + 0, S1, Q1, n, nwaves, s);
  affine_k<<<dim3(1), dim3(DIMS), 0, stream>>>(S1, Q1, gamma1, beta1, affA + DIMS, affB + DIMS, invn);
  // fold stage-1 affine into transposed fp16 weights, then MFMA matmul (stats -> S2/Q2)
  foldw_k<<<dim3(DIMS), dim3(DIMS), 0, stream>>>(conv_w, conv_b, affA + DIMS, affB + DIMS, Wt, cp);
  matmul_k<<<dim3((n + 127) / 128), dim3(256), 0, stream>>>(
      (const uint4*)Y2, (const uint4*)Wt, cp, (uint4*)Zh, S2, Q2, n);
  affine_k<<<dim3(1), dim3(DIMS), 0, stream>>>(S2, Q2, gamma2, beta2, affA + 2 * DIMS, affB + 2 * DIMS, invn);
  // pooling + prediction
  gstart_k<<<dim3((n + 255) / 256), dim3(256), 0, stream>>>(n2g, gstart, n, g);
  pool_pred_k<<<dim3(g), dim3(512), 0, stream>>>((const uint4*)Zh, gstart,
                                                 affA + 2 * DIMS, affB + 2 * DIMS,
                                                 pred_w, pred_b, out);
}

// Round 14
// 257.246 us; speedup vs baseline: 2.5881x; 2.5881x over previous
//
#include <hip/hip_runtime.h>
#include <hip/hip_fp16.h>
#include <cstddef>
#include <cstdint>

constexpr int DIMS = 128;
constexpr float BN_EPS = 1e-5f;
constexpr int NSH = 64;   // stat shadow copies
constexpr int GB = 4096;  // gather grid blocks (x4 waves = 16384 waves)
constexpr int NPB = 512;  // partition blocks for CSR build

typedef _Float16 f16x8 __attribute__((ext_vector_type(8)));
typedef float f32x4 __attribute__((ext_vector_type(4)));

static __device__ __forceinline__ f16x8 as_f16x8(uint4 u) {
  union { uint4 u; f16x8 h; } x; x.u = u; return x.h;
}
static __device__ __forceinline__ __half2 as_h2(uint32_t u) {
  union { uint32_t u; __half2 h; } x; x.u = u; return x.h;
}

// ---------------- utility ----------------
__global__ void zero_k(float* __restrict__ fp, size_t nf) {
  size_t i = (size_t)blockIdx.x * blockDim.x + threadIdx.x;
  if (i < nf) fp[i] = 0.f;
}

// fp32 -> fp16 conversion with dn pre-scale: Xp[s] = dn[s] * nfeat[s]
__global__ void cvt_k(const float* __restrict__ in, uint32_t* __restrict__ out,
                      const float* __restrict__ dnorm, size_t n64) {
  size_t i = (size_t)blockIdx.x * blockDim.x + threadIdx.x;
  size_t stride = (size_t)gridDim.x * blockDim.x;
  const float2* in2 = (const float2*)in;
  for (; i < n64; i += stride) {
    float d = dnorm[i >> 6];
    float2 v = in2[i];
    __half2 h = __floats2half2_rn(v.x * d, v.y * d);
    out[i] = *(const uint32_t*)&h;
  }
}

// ---------------- two-pass binned CSR build (no global atomics) ----------------
// bins of 512 nodes; nbins <= 512 (n <= 262144). C layout: C[block*512 + bin].

__global__ __launch_bounds__(256) void cnt_k(const int* __restrict__ dst,
                                             int* __restrict__ C, int e, int chunk) {
  __shared__ int hist[512];
  int b = blockIdx.x;
  for (int j = threadIdx.x; j < 512; j += 256) hist[j] = 0;
  __syncthreads();
  int i0 = b * chunk;
  int i1 = i0 + chunk; if (i1 > e) i1 = e;
  for (int i = i0 + threadIdx.x; i < i1; i += 256)
    atomicAdd(&hist[dst[i] >> 9], 1);
  __syncthreads();
  for (int j = threadIdx.x; j < 512; j += 256) C[b * 512 + j] = hist[j];
}

__global__ __launch_bounds__(512) void colscan_k(int* __restrict__ C, int* __restrict__ tot) {
  int j = blockIdx.x;   // bin
  int t = threadIdx.x;  // partition block
  int v = C[t * 512 + j];
  __shared__ int lds[512];
  lds[t] = v; __syncthreads();
  for (int off = 1; off < 512; off <<= 1) {
    int add = (t >= off) ? lds[t - off] : 0;
    __syncthreads();
    lds[t] += add;
    __syncthreads();
  }
  C[t * 512 + j] = lds[t] - v;  // exclusive within-column prefix
  if (t == 511) tot[j] = lds[511];
}

__global__ __launch_bounds__(512) void bscan_k(const int* __restrict__ tot, int nbins,
                                               int* __restrict__ boff, int e) {
  int t = threadIdx.x;
  int v = tot[t];
  __shared__ int lds[512];
  lds[t] = v; __syncthreads();
  for (int off = 1; off < 512; off <<= 1) {
    int add = (t >= off) ? lds[t - off] : 0;
    __syncthreads();
    lds[t] += add;
    __syncthreads();
  }
  boff[t] = lds[t] - v;
  if (t == 0) boff[nbins] = e;
}

// scatter edges to bin-grouped ebin using LDS-only cursors
__global__ __launch_bounds__(256) void scat_k(const int* __restrict__ src,
                                              const int* __restrict__ dst,
                                              const int* __restrict__ C,
                                              const int* __restrict__ boff,
                                              int* __restrict__ ebin, int e, int chunk) {
  __shared__ int cur[512];
  int b = blockIdx.x;
  for (int j = threadIdx.x; j < 512; j += 256) cur[j] = boff[j] + C[b * 512 + j];
  __syncthreads();
  int i0 = b * chunk;
  int i1 = i0 + chunk; if (i1 > e) i1 = e;
  for (int i = i0 + threadIdx.x; i < i1; i += 256) {
    int d = dst[i];
    int bin = d >> 9;
    int p = atomicAdd(&cur[bin], 1);
    ebin[p] = (src[i] << 9) | (d & 511);
  }
}

// fused per-bin: degree histogram -> LDS scan -> row_off + dnorm
__global__ __launch_bounds__(512) void binidx_k(
    const int* __restrict__ ebin, const int* __restrict__ boff,
    int* __restrict__ row_off, float* __restrict__ dnorm, int n, int nbins) {
  __shared__ int cnt[512];
  __shared__ int scn[512];
  int b = blockIdx.x;
  int t = threadIdx.x;
  cnt[t] = 0;
  __syncthreads();
  int j0 = boff[b], j1 = boff[b + 1];
  for (int i = j0 + t; i < j1; i += 512) atomicAdd(&cnt[ebin[i] & 511], 1);
  __syncthreads();
  int v = cnt[t];
  scn[t] = v; __syncthreads();
  for (int off = 1; off < 512; off <<= 1) {
    int add = (t >= off) ? scn[t - off] : 0;
    __syncthreads();
    scn[t] += add;
    __syncthreads();
  }
  int node = (b << 9) + t;
  if (node < n) {
    row_off[node] = j0 + scn[t] - v;
    dnorm[node] = rsqrtf(fmaxf((float)v, 1.0f));
  }
  if (b == nbins - 1 && t == 0) row_off[n] = j1;  // j1 == e for last bin
}

// adj placement (bin-local, L2-hot) + wsum[node] = sum dn[src] via LDS accumulators
__global__ __launch_bounds__(512) void adj_bins_k(
    const int* __restrict__ ebin, const int* __restrict__ boff,
    const int* __restrict__ row_off, const float* __restrict__ dnorm,
    int* __restrict__ adj, float* __restrict__ wsum, int n) {
  __shared__ int cur[512];
  __shared__ int ro[512];
  __shared__ float ws[512];
  int b = blockIdx.x;
  int base = b << 9;
  int t = threadIdx.x;
  {
    cur[t] = 0;
    ws[t] = 0.f;
    int node = base + t;
    ro[t] = (node < n) ? row_off[node] : 0;
  }
  __syncthreads();
  int j0 = boff[b], j1 = boff[b + 1];
  for (int i = j0 + t; i < j1; i += 512) {
    int pk = ebin[i];
    int dl = pk & 511;
    int s = pk >> 9;
    int p = atomicAdd(&cur[dl], 1);
    adj[ro[dl] + p] = s;
    atomicAdd(&ws[dl], dnorm[s]);
  }
  __syncthreads();
  {
    int node = base + t;
    if (node < n) wsum[node] = ws[t];
  }
}

// ---------------- propagation hop: grid-stride, TWO nodes per wave in flight -------
// Lane owns 2 features (half2 row element). 8-deep edge pipeline per node stream.
// AFF=false (hop1): acc = sum Xp[s]; v = dn*acc (stats); store W1 = dn*v = dn^2*acc.
// AFF=true  (hop2): acc = sum W1[s]; v = dn*(a*acc + b*wsum[n]) (stats); store v.
template <bool AFF>
__global__ __launch_bounds__(256) void gather_k(
    const uint32_t* __restrict__ Xu, uint32_t* __restrict__ Yout,
    const int* __restrict__ row_off, const int* __restrict__ adj,
    const float* __restrict__ dn, const float* __restrict__ wsum,
    const float* __restrict__ a, const float* __restrict__ b,
    float* __restrict__ sumS, float* __restrict__ sqS, int n, int nwaves) {
  int tid = threadIdx.x;
  int l = tid & 63, w = tid >> 6;
  int wid = blockIdx.x * 4 + w;  // wave-uniform
  uint32_t lu = (uint32_t)l;
  int f0 = 2 * l;
  float af0 = 1.f, bf0 = 0.f, af1 = 1.f, bf1 = 0.f;
  if (AFF) { af0 = a[f0]; bf0 = b[f0]; af1 = a[f0 + 1]; bf1 = b[f0 + 1]; }
  float s0 = 0.f, s1 = 0.f, q0 = 0.f, q1 = 0.f;

  for (int nodeA = wid; nodeA < n; nodeA += 2 * nwaves) {
    const int nodeB = nodeA + nwaves;
    const bool hasB = nodeB < n;
    int ja = row_off[nodeA];
    const int ea = row_off[nodeA + 1];
    int jb = hasB ? row_off[nodeB] : 0;
    const int eb = hasB ? row_off[nodeB + 1] : 0;
    float accA0 = 0.f, accA1 = 0.f, accB0 = 0.f, accB1 = 0.f;

    while ((ja < ea) || (jb < eb)) {
      uint32_t xa[8], xb[8];
      const bool runA = ja < ea, runB = jb < eb;
      if (runA) {  // issue 8 loads for stream A
#pragma unroll
        for (int t = 0; t < 8; ++t) {
          int jj = ja + t;
          int jc = jj < ea ? jj : ea - 1;
          uint32_t sj = (uint32_t)adj[jc];
          uint32_t v = Xu[(sj << 6) + lu];
          xa[t] = (jj < ea) ? v : 0u;
        }
      }
      if (runB) {  // issue 8 more (independent -> 16 in flight)
#pragma unroll
        for (int t = 0; t < 8; ++t) {
          int jj = jb + t;
          int jc = jj < eb ? jj : eb - 1;
          uint32_t sj = (uint32_t)adj[jc];
          uint32_t v = Xu[(sj << 6) + lu];
          xb[t] = (jj < eb) ? v : 0u;
        }
      }
      if (runA) {  // depth-2 fp16 pairwise tree, fp32 accumulate
        __half2 t0 = __hadd2(as_h2(xa[0]), as_h2(xa[1]));
        __half2 t1 = __hadd2(as_h2(xa[2]), as_h2(xa[3]));
        __half2 t2 = __hadd2(as_h2(xa[4]), as_h2(xa[5]));
        __half2 t3 = __hadd2(as_h2(xa[6]), as_h2(xa[7]));
        float2 u0 = __half22float2(__hadd2(t0, t1));
        float2 u1 = __half22float2(__hadd2(t2, t3));
        accA0 += u0.x + u1.x;
        accA1 += u0.y + u1.y;
        ja += 8;
      }
      if (runB) {
        __half2 t0 = __hadd2(as_h2(xb[0]), as_h2(xb[1]));
        __half2 t1 = __hadd2(as_h2(xb[2]), as_h2(xb[3]));
        __half2 t2 = __hadd2(as_h2(xb[4]), as_h2(xb[5]));
        __half2 t3 = __hadd2(as_h2(xb[6]), as_h2(xb[7]));
        float2 u0 = __half22float2(__hadd2(t0, t1));
        float2 u1 = __half22float2(__hadd2(t2, t3));
        accB0 += u0.x + u1.x;
        accB1 += u0.y + u1.y;
        jb += 8;
      }
    }

    {  // finalize node A
      float dnn = dn[nodeA];
      float v0, v1;
      if constexpr (AFF) {
        float wsn = wsum[nodeA];
        v0 = dnn * fmaf(af0, accA0, bf0 * wsn);
        v1 = dnn * fmaf(af1, accA1, bf1 * wsn);
        __half2 hv = __floats2half2_rn(v0, v1);
        Yout[((uint32_t)nodeA << 6) + lu] = *(const uint32_t*)&hv;
      } else {
        v0 = dnn * accA0;
        v1 = dnn * accA1;
        __half2 hv = __floats2half2_rn(v0 * dnn, v1 * dnn);  // W1 = dn^2*acc
        Yout[((uint32_t)nodeA << 6) + lu] = *(const uint32_t*)&hv;
      }
      s0 += v0; s1 += v1; q0 += v0 * v0; q1 += v1 * v1;
    }
    if (hasB) {  // finalize node B
      float dnn = dn[nodeB];
      float v0, v1;
      if constexpr (AFF) {
        float wsn = wsum[nodeB];
        v0 = dnn * fmaf(af0, accB0, bf0 * wsn);
        v1 = dnn * fmaf(af1, accB1, bf1 * wsn);
        __half2 hv = __floats2half2_rn(v0, v1);
        Yout[((uint32_t)nodeB << 6) + lu] = *(const uint32_t*)&hv;
      } else {
        v0 = dnn * accB0;
        v1 = dnn * accB1;
        __half2 hv = __floats2half2_rn(v0 * dnn, v1 * dnn);
        Yout[((uint32_t)nodeB << 6) + lu] = *(const uint32_t*)&hv;
      }
      s0 += v0; s1 += v1; q0 += v0 * v0; q1 += v1 * v1;
    }
  }

  // block epilogue: LDS cross-wave reduce, then 256 lane-atomics per block
  __shared__ float red[4][256];
  red[w][l] = s0; red[w][64 + l] = s1; red[w][128 + l] = q0; red[w][192 + l] = q1;
  __syncthreads();
  float t = red[0][tid] + red[1][tid] + red[2][tid] + red[3][tid];
  int comp = tid >> 6, li = tid & 63;
  int sh = blockIdx.x & (NSH - 1);
  float* dstp = ((comp & 2) ? sqS : sumS) + sh * DIMS;
  atomicAdd(&dstp[2 * li + (comp & 1)], t);
}

// ---------------- BN affine coefficients (reduces NSH shadow copies) ----------------
__global__ void affine_k(const float* __restrict__ sum, const float* __restrict__ sq,
                         const float* __restrict__ gamma, const float* __restrict__ beta,
                         float* __restrict__ a, float* __restrict__ b, float invn) {
  int d = threadIdx.x;
  float s = 0.f, q = 0.f;
  for (int k = 0; k < NSH; ++k) { s += sum[k * DIMS + d]; q += sq[k * DIMS + d]; }
  float mu = s * invn;
  float var = q * invn - mu * mu;
  float rs = rsqrtf(var + BN_EPS);
  float ad = rs * gamma[d];
  a[d] = ad;
  b[d] = beta[d] - mu * ad;
}

// fold pre-matmul affine into weights, TRANSPOSED fp16:
// Wt[o][d] = (half)(a2[d]*W[d][o]);  cp[o] = sum_d b2[d]*W[d][o] + cb[o]
__global__ void foldw_k(const float* __restrict__ W, const float* __restrict__ cb,
                        const float* __restrict__ a2, const float* __restrict__ b2,
                        __half* __restrict__ Wt, float* __restrict__ cp) {
  int o = blockIdx.x;
  int d = threadIdx.x;
  float w = W[d * DIMS + o];
  Wt[o * DIMS + d] = __float2half(a2[d] * w);
  __shared__ float red[128];
  red[d] = b2[d] * w;
  __syncthreads();
  for (int off = 64; off > 0; off >>= 1) {
    if (d < off) red[d] += red[d + off];
    __syncthreads();
  }
  if (d == 0) cp[o] = red[0] + cb[o];
}

// ---------------- Z = X @ W + cp via MFMA, 32 rows/wave, LDS-staged stores ----------
__global__ __launch_bounds__(256) void matmul_k(
    const uint4* __restrict__ X, const uint4* __restrict__ Wt,
    const float* __restrict__ cp, uint4* __restrict__ Z,
    float* __restrict__ sumS, float* __restrict__ sqS, int n) {
  int tid = threadIdx.x;
  int l = tid & 63, w = tid >> 6;
  int rowg = l & 15;  // A-row / B-col / D-col within tile
  int kg = l >> 4;    // k-group
  int r0 = (blockIdx.x * 4 + w) * 32;
  bool active = r0 < n;

  __shared__ __half outs[4][16][136];  // per-wave staging, +8 halves row pad
  __shared__ float sred[4][128], qred[4][128];
  float svals[8], qvals[8];

  if (active) {
    f32x4 acc0[8] = {}, acc1[8] = {};
    const uint4* xr0 = X + (size_t)(r0 + rowg) * 16;
    const uint4* xr1 = X + (size_t)(r0 + 16 + rowg) * 16;
    bool ok0 = (r0 + rowg) < n;
    bool ok1 = (r0 + 16 + rowg) < n;
#pragma unroll
    for (int kk = 0; kk < 4; ++kk) {
      uint4 au0 = ok0 ? xr0[kk * 4 + kg] : make_uint4(0u, 0u, 0u, 0u);
      uint4 au1 = ok1 ? xr1[kk * 4 + kg] : make_uint4(0u, 0u, 0u, 0u);
      f16x8 a0 = as_f16x8(au0), a1 = as_f16x8(au1);
#pragma unroll
      for (int c = 0; c < 8; ++c) {
        f16x8 bfr = as_f16x8(Wt[(size_t)(c * 16 + rowg) * 16 + kk * 4 + kg]);
        acc0[c] = __builtin_amdgcn_mfma_f32_16x16x32_f16(a0, bfr, acc0[c], 0, 0, 0);
        acc1[c] = __builtin_amdgcn_mfma_f32_16x16x32_f16(a1, bfr, acc1[c], 0, 0, 0);
      }
    }
#pragma unroll
    for (int c = 0; c < 8; ++c) { svals[c] = 0.f; qvals[c] = 0.f; }
#pragma unroll
    for (int gidx = 0; gidx < 2; ++gidx) {
      int rbase = r0 + gidx * 16;
#pragma unroll
      for (int c = 0; c < 8; ++c) {
        float cpv = cp[c * 16 + rowg];
        f32x4 av = (gidx == 0) ? acc0[c] : acc1[c];
#pragma unroll
        for (int r = 0; r < 4; ++r) {
          int row = rbase + kg * 4 + r;
          float vv = av[r] + cpv;
          vv = (row < n) ? vv : 0.f;
          svals[c] += vv; qvals[c] += vv * vv;
          outs[w][kg * 4 + r][c * 16 + rowg] = __float2half(vv);
        }
      }
      // coalesced store of this 16-row group (wave-local LDS, in-order per wave)
#pragma unroll
      for (int it = 0; it < 4; ++it) {
        int lr = it * 4 + kg;
        int grow = rbase + lr;
        if (grow < n)
          Z[(size_t)grow * 16 + rowg] = *(const uint4*)&outs[w][lr][rowg * 8];
      }
    }
#pragma unroll
    for (int c = 0; c < 8; ++c) {
      svals[c] += __shfl_xor(svals[c], 16); svals[c] += __shfl_xor(svals[c], 32);
      qvals[c] += __shfl_xor(qvals[c], 16); qvals[c] += __shfl_xor(qvals[c], 32);
    }
  }
  if (active) {
    if (kg == 0) {
#pragma unroll
      for (int c = 0; c < 8; ++c) {
        sred[w][c * 16 + rowg] = svals[c];
        qred[w][c * 16 + rowg] = qvals[c];
      }
    }
  } else {
    sred[w][l] = 0.f; sred[w][64 + l] = 0.f;
    qred[w][l] = 0.f; qred[w][64 + l] = 0.f;
  }
  __syncthreads();
  int f = tid & 127;
  int sh = blockIdx.x & (NSH - 1);
  if (tid < 128) {
    float s = sred[0][f] + sred[1][f] + sred[2][f] + sred[3][f];
    atomicAdd(&sumS[sh * DIMS + f], s);
  } else {
    float q = qred[0][f] + qred[1][f] + qred[2][f] + qred[3][f];
    atomicAdd(&sqS[sh * DIMS + f], q);
  }
}

// ---------------- graph segment starts (node2graph is sorted) ----------------
__global__ void gstart_k(const int* __restrict__ n2g, int* __restrict__ gstart, int n, int G) {
  int i = blockIdx.x * blockDim.x + threadIdx.x;
  if (i >= n) return;
  int g = n2g[i];
  int gp = (i == 0) ? -1 : n2g[i - 1];
  for (int x = gp + 1; x <= g; ++x) gstart[x] = i;
  if (i == n - 1) {
    for (int x = g + 1; x <= G; ++x) gstart[x] = n;
  }
}

// ---------------- BN2-apply + relu + mean-pool + 128->2 projection ----------------
__global__ __launch_bounds__(512) void pool_pred_k(
    const uint4* __restrict__ Z, const int* __restrict__ gstart,
    const float* __restrict__ a3, const float* __restrict__ b3,
    const float* __restrict__ pw, const float* __restrict__ pb,
    float* __restrict__ out) {
  int g = blockIdx.x;
  int tid = threadIdx.x;
  int l = tid & 63, w = tid >> 6;  // w 0..7
  int grp = l >> 4, fl = l & 15;
  int f0 = fl * 8;
  float av[8], bv[8];
#pragma unroll
  for (int q = 0; q < 8; ++q) { av[q] = a3[f0 + q]; bv[q] = b3[f0 + q]; }
  int s = gstart[g], e = gstart[g + 1];
  float rs[8] = {0.f, 0.f, 0.f, 0.f, 0.f, 0.f, 0.f, 0.f};
  for (int ni = s + (w * 4 + grp); ni < e; ni += 32) {
    uint4 zv = Z[(size_t)ni * 16 + fl];
    const __half2* h = (const __half2*)&zv;
#pragma unroll
    for (int q = 0; q < 4; ++q) {
      float2 z = __half22float2(h[q]);
      rs[2 * q] += fmaxf(fmaf(z.x, av[2 * q], bv[2 * q]), 0.f);
      rs[2 * q + 1] += fmaxf(fmaf(z.y, av[2 * q + 1], bv[2 * q + 1]), 0.f);
    }
  }
  float p0 = 0.f, p1 = 0.f;
#pragma unroll
  for (int q = 0; q < 8; ++q) {
    p0 += rs[q] * pw[(f0 + q) * 2 + 0];
    p1 += rs[q] * pw[(f0 + q) * 2 + 1];
  }
  __shared__ float r[2][512];
  r[0][tid] = p0; r[1][tid] = p1;
  __syncthreads();
  for (int off = 256; off > 0; off >>= 1) {
    if (tid < off) { r[0][tid] += r[0][tid + off]; r[1][tid] += r[1][tid + off]; }
    __syncthreads();
  }
  if (tid == 0) {
    float inv = 1.f / fmaxf((float)(e - s), 1.f);
    out[g * 2 + 0] = r[0][0] * inv + pb[0];
    out[g * 2 + 1] = r[1][0] * inv + pb[1];
  }
}

// ---------------- host launch ----------------
extern "C" void kernel_launch(void* const* d_in, const int* in_sizes, int n_in,
                              void* d_out, int out_size, void* d_ws, size_t ws_size,
                              hipStream_t stream) {
  const float* nfeat  = (const float*)d_in[0];
  const int*   src    = (const int*)d_in[1];
  const int*   dst    = (const int*)d_in[2];
  const int*   n2g    = (const int*)d_in[3];
  // d_in[4] = num_graphs (device scalar) — derived from out_size instead
  const float* conv_w = (const float*)d_in[5];
  const float* conv_b = (const float*)d_in[6];
  const float* gamma1 = (const float*)d_in[7];
  const float* beta1  = (const float*)d_in[8];
  const float* gamma2 = (const float*)d_in[9];
  const float* beta2  = (const float*)d_in[10];
  const float* pred_w = (const float*)d_in[11];
  const float* pred_b = (const float*)d_in[12];
  float* out = (float*)d_out;
  (void)n_in; (void)ws_size;

  const int n = in_sizes[0] / DIMS;
  const int e = in_sizes[1];
  const int g = out_size / 2;
  const int nbins = (n + 511) >> 9;  // <= 512 (n <= 262144)

  char* p = (char*)d_ws;
  auto alloc = [&](size_t bytes) { char* r = p; p += (bytes + 255) & ~(size_t)255; return r; };
  uint32_t* Xp  = (uint32_t*)alloc((size_t)n * 64 * 4);  // dn-scaled input rows (fp16)
  uint32_t* W1  = (uint32_t*)alloc((size_t)n * 64 * 4);  // dn^2-scaled h1 rows (fp16)
  uint32_t* Y2  = (uint32_t*)alloc((size_t)n * 64 * 4);  // h2 rows (fp16)
  __half*   Zh  = (__half*)alloc((size_t)n * 64 * 4);    // matmul output rows (fp16)
  float* dnorm = (float*)alloc((size_t)n * 4);
  float* stat  = (float*)alloc(((size_t)6 * NSH * DIMS + n) * 4);  // stats + wsum
  float* wsum  = stat + 6 * NSH * DIMS;
  float* affA  = (float*)alloc(3 * DIMS * 4);
  float* affB  = (float*)alloc(3 * DIMS * 4);
  __half* Wt   = (__half*)alloc(DIMS * DIMS * 2);
  float* cp    = (float*)alloc(DIMS * 4);
  int* row_off = (int*)alloc(((size_t)n + 1) * 4);
  int* adj     = (int*)alloc((size_t)e * 4);
  int* ebin    = (int*)alloc((size_t)e * 4);
  int* Cmat    = (int*)alloc((size_t)NPB * 512 * 4);
  int* tot     = (int*)alloc(512 * 4);
  int* boff    = (int*)alloc(520 * 4);
  int* gstart  = (int*)alloc(((size_t)g + 1) * 4);

  const int SLAB = NSH * DIMS;
  float* S0 = stat + 0 * SLAB; float* Q0 = stat + 1 * SLAB;
  float* S1 = stat + 2 * SLAB; float* Q1 = stat + 3 * SLAB;
  float* S2 = stat + 4 * SLAB; float* Q2 = stat + 5 * SLAB;

  const float invn = 1.0f / (float)n;
  const int nwaves = GB * 4;
  const int chunk = (e + NPB - 1) / NPB;

  // zero stats
  zero_k<<<dim3(((size_t)6 * SLAB + 255) / 256), dim3(256), 0, stream>>>(stat, (size_t)6 * SLAB);
  // two-pass binned CSR build (no global atomics)
  cnt_k<<<dim3(NPB), dim3(256), 0, stream>>>(dst, Cmat, e, chunk);
  colscan_k<<<dim3(512), dim3(512), 0, stream>>>(Cmat, tot);
  bscan_k<<<dim3(1), dim3(512), 0, stream>>>(tot, nbins, boff, e);
  scat_k<<<dim3(NPB), dim3(256), 0, stream>>>(src, dst, Cmat, boff, ebin, e, chunk);
  binidx_k<<<dim3(nbins), dim3(512), 0, stream>>>(ebin, boff, row_off, dnorm, n, nbins);
  cvt_k<<<dim3(2048), dim3(256), 0, stream>>>(nfeat, Xp, dnorm, (size_t)n * 64);
  adj_bins_k<<<dim3(nbins), dim3(512), 0, stream>>>(ebin, boff, row_off, dnorm, adj, wsum, n);

  // hop 1: Xp -> W1 (stats of h1 -> S0/Q0)
  gather_k<false><<<dim3(GB), dim3(256), 0, stream>>>(
      Xp, W1, row_off, adj, dnorm, wsum, nullptr, nullptr, S0, Q0, n, nwaves);
  affine_k<<<dim3(1), dim3(DIMS), 0, stream>>>(S0, Q0, gamma1, beta1, affA + 0, affB + 0, invn);
  // hop 2: W1 -> Y2 = h2 (stats -> S1/Q1)
  gather_k<true><<<dim3(GB), dim3(256), 0, stream>>>(
      W1, Y2, row_off, adj, dnorm, wsum, affA + 0, affB + 0, S1, Q1, n, nwaves);
  affine_k<<<dim3(1), dim3(DIMS), 0, stream>>>(S1, Q1, gamma1, beta1, affA + DIMS, affB + DIMS, invn);
  // fold stage-1 affine into transposed fp16 weights, then MFMA matmul (stats -> S2/Q2)
  foldw_k<<<dim3(DIMS), dim3(DIMS), 0, stream>>>(conv_w, conv_b, affA + DIMS, affB + DIMS, Wt, cp);
  matmul_k<<<dim3((n + 127) / 128), dim3(256), 0, stream>>>(
      (const uint4*)Y2, (const uint4*)Wt, cp, (uint4*)Zh, S2, Q2, n);
  affine_k<<<dim3(1), dim3(DIMS), 0, stream>>>(S2, Q2, gamma2, beta2, affA + 2 * DIMS, affB + 2 * DIMS, invn);
  // pooling + prediction
  gstart_k<<<dim3((n + 255) / 256), dim3(256), 0, stream>>>(n2g, gstart, n, g);
  pool_pred_k<<<dim3(g), dim3(512), 0, stream>>>((const uint4*)Zh, gstart,
                                                 affA + 2 * DIMS, affB + 2 * DIMS,
                                                 pred_w, pred_b, out);
}